// Round 1
// baseline (3670.839 us; speedup 1.0000x reference)
//
#include <hip/hip_runtime.h>
#include <stdint.h>

typedef unsigned short u16;
typedef __attribute__((ext_vector_type(8))) short bf16x8;
typedef __attribute__((ext_vector_type(4))) float f32x4;

#define EE 512
#define NH 8
#define HDm 64
#define SS 128
#define NB 8
#define NL 4

__device__ __forceinline__ float bf2f(u16 v){ union{uint32_t u; float f;} c; c.u=((uint32_t)v)<<16; return c.f; }
__device__ __forceinline__ u16 f2bf(float f){ union{float f; uint32_t u;} c; c.f=f; uint32_t u=c.u; return (u16)((u + 0x7FFFu + ((u>>16)&1u))>>16); }

__device__ __forceinline__ f32x4 mfma16(bf16x8 a, bf16x8 b, f32x4 c){
  return __builtin_amdgcn_mfma_f32_16x16x32_bf16(a,b,c,0,0,0);
}

__device__ __forceinline__ void gload16(const u16* g, u16* l){
  auto gp = reinterpret_cast<const __attribute__((address_space(1))) uint32_t*>(reinterpret_cast<uintptr_t>(g));
  auto lp = reinterpret_cast<__attribute__((address_space(3))) uint32_t*>(reinterpret_cast<uintptr_t>(l));
  __builtin_amdgcn_global_load_lds(gp, lp, 16, 0, 0);
}

// Wt[l][o][i] = bf16(W[l][i][o])
__global__ __launch_bounds__(256) void wtrans(const float* __restrict__ W, u16* __restrict__ Wt){
  int i = blockIdx.x*256 + threadIdx.x;
  int l = i >> 18;
  int rem = i & 262143;
  int o = rem >> 9, in_ = rem & 511;
  Wt[i] = f2bf(W[((size_t)l<<18) + ((size_t)in_<<9) + (size_t)o]);
}

// h[r][b][p][e] = bf16(x[b][p][e]) for RC runs
__global__ __launch_bounds__(256) void hinit(const float* __restrict__ x, u16* __restrict__ h){
  size_t i = ((size_t)blockIdx.x*256 + threadIdx.x)*8;
  size_t within = i % ((size_t)NB*SS*EE);
  const float* xp = x + within;
  union{ bf16x8 v; u16 u[8]; } r;
  #pragma unroll
  for (int j=0;j<8;j++) r.u[j] = f2bf(xp[j]);
  *(bf16x8*)(h + i) = r.v;
}

// C = A[M x 512] * Bt^T  (Bt is [512 out][512 in]), + bias; MODE 0: +bias, 1: +bias+res, 2: relu(+bias)+res
template<int MODE>
__global__ __launch_bounds__(256) void gemm_bt(const u16* __restrict__ A, const u16* __restrict__ Bt,
                                               const float* __restrict__ bias, const u16* __restrict__ res,
                                               u16* __restrict__ out){
  __shared__ u16 As[128*32];
  __shared__ u16 Bs[128*32];
  int t = threadIdx.x;
  size_t m0 = (size_t)blockIdx.x*128;
  int n0 = blockIdx.y*128;
  int wid=t>>6, lane=t&63;
  int wm=wid>>1, wn=wid&1, lr=lane&15, lk=(lane>>4)*8;
  f32x4 acc[4][4] = {};
  int srow=t>>2, scol=(t&3)*8;
  const u16* gA = A + (m0+(size_t)srow)*EE + scol;
  const u16* gB = Bt + ((size_t)(n0+srow))*EE + scol;
  u16* lA = As + t*8;
  u16* lB = Bs + t*8;
  for (int k0=0;k0<EE;k0+=32){
    __syncthreads();
    gload16(gA+k0, lA);
    gload16(gA+64*EE+k0, lA+2048);
    gload16(gB+k0, lB);
    gload16(gB+64*EE+k0, lB+2048);
    __syncthreads();
    bf16x8 a[4], b[4];
    #pragma unroll
    for (int mi=0;mi<4;mi++) a[mi] = *(const bf16x8*)(As + (wm*64+mi*16+lr)*32 + lk);
    #pragma unroll
    for (int ni=0;ni<4;ni++) b[ni] = *(const bf16x8*)(Bs + (wn*64+ni*16+lr)*32 + lk);
    #pragma unroll
    for (int mi=0;mi<4;mi++)
      #pragma unroll
      for (int ni=0;ni<4;ni++)
        acc[mi][ni] = mfma16(a[mi], b[ni], acc[mi][ni]);
  }
  int g4 = lane>>4;
  #pragma unroll
  for (int ni=0;ni<4;ni++){
    int col = n0 + wn*64 + ni*16 + lr;
    float bv = bias[col];
    #pragma unroll
    for (int mi=0;mi<4;mi++){
      #pragma unroll
      for (int j=0;j<4;j++){
        size_t row = m0 + (size_t)(wm*64 + mi*16 + g4*4 + j);
        float v = acc[mi][ni][j] + bv;
        if (MODE==2) v = fmaxf(v, 0.f);
        if (MODE>=1) v += bf2f(res[row*EE + col]);
        out[row*EE + col] = f2bf(v);
      }
    }
  }
}

// one block per (run, batch, head); 4 waves, 2 q-tiles each
__global__ __launch_bounds__(256) void attn(const u16* __restrict__ Q, const u16* __restrict__ K,
                                            const u16* __restrict__ V, u16* __restrict__ O, int cb){
  __shared__ u16 Ks[128*72];     // [key][d], pad 8
  __shared__ u16 Vt[64*136];     // [d][key], pad 8
  __shared__ u16 Ps[4][16*136];  // per-wave P [q][key], pad 8
  int t = threadIdx.x;
  int idx = blockIdx.x;
  int hh = idx & 7, b = (idx>>3)&7, r = idx>>6;
  int m_run = cb + r;
  size_t base = ((size_t)(r*NB + b)*SS)*EE + hh*HDm;
  for (int i=t; i<1024; i+=256){
    int row=i>>3, c=(i&7)*8;
    *(uint4*)(Ks + row*72 + c) = *(const uint4*)(K + base + (size_t)row*EE + c);
  }
  for (int i=t; i<1024; i+=256){
    int row=i>>3, c=(i&7)*8;
    uint4 raw = *(const uint4*)(V + base + (size_t)row*EE + c);
    const u16* pv = (const u16*)&raw;
    #pragma unroll
    for (int j=0;j<8;j++) Vt[(c+j)*136 + row] = pv[j];
  }
  __syncthreads();
  int wid=t>>6, lane=t&63, lr=lane&15, g=lane>>4, lk=(lane>>4)*8;
  int nkc = m_run/32 + 1;   // 1..4 key chunks of 32
  int nkt = nkc*2;          // 2..8 key tiles of 16
  u16* Pw = Ps[wid];
  for (int iq=0; iq<2; iq++){
    int qt = wid*2 + iq;
    const u16* qrow = Q + base + (size_t)(qt*16+lr)*EE;
    bf16x8 qa0 = *(const bf16x8*)(qrow + lk);
    bf16x8 qa1 = *(const bf16x8*)(qrow + 32 + lk);
    f32x4 sc[8];
    #pragma unroll
    for (int kt=0;kt<8;kt++){
      if (kt < nkt){
        f32x4 c = {};
        bf16x8 kb0 = *(const bf16x8*)(Ks + (kt*16+lr)*72 + lk);
        bf16x8 kb1 = *(const bf16x8*)(Ks + (kt*16+lr)*72 + 32 + lk);
        c = mfma16(qa0, kb0, c);
        c = mfma16(qa1, kb1, c);
        int key = kt*16 + lr;
        #pragma unroll
        for (int i2=0;i2<4;i2++)
          sc[kt][i2] = (key <= m_run) ? c[i2]*0.125f : -1e9f;
      }
    }
    #pragma unroll
    for (int i2=0;i2<4;i2++){
      float v = -3.0e38f;
      #pragma unroll
      for (int kt=0;kt<8;kt++) if (kt<nkt) v = fmaxf(v, sc[kt][i2]);
      v = fmaxf(v, __shfl_xor(v,1));
      v = fmaxf(v, __shfl_xor(v,2));
      v = fmaxf(v, __shfl_xor(v,4));
      v = fmaxf(v, __shfl_xor(v,8));
      float s = 0.f;
      #pragma unroll
      for (int kt=0;kt<8;kt++) if (kt<nkt){ float e2=__expf(sc[kt][i2]-v); sc[kt][i2]=e2; s+=e2; }
      s += __shfl_xor(s,1); s += __shfl_xor(s,2); s += __shfl_xor(s,4); s += __shfl_xor(s,8);
      float inv = 1.f/s;
      #pragma unroll
      for (int kt=0;kt<8;kt++) if (kt<nkt) sc[kt][i2] *= inv;
    }
    #pragma unroll
    for (int kt=0;kt<8;kt++) if (kt<nkt){
      #pragma unroll
      for (int i2=0;i2<4;i2++)
        Pw[(g*4+i2)*136 + kt*16 + lr] = f2bf(sc[kt][i2]);
    }
    __syncthreads();
    f32x4 oa[4] = {};
    #pragma unroll
    for (int kc=0;kc<4;kc++) if (kc<nkc){
      bf16x8 pa = *(const bf16x8*)(Pw + lr*136 + kc*32 + lk);
      #pragma unroll
      for (int dt=0;dt<4;dt++){
        bf16x8 vb = *(const bf16x8*)(Vt + (dt*16+lr)*136 + kc*32 + lk);
        oa[dt] = mfma16(pa, vb, oa[dt]);
      }
    }
    #pragma unroll
    for (int dt=0;dt<4;dt++){
      #pragma unroll
      for (int j=0;j<4;j++){
        size_t row = (size_t)(qt*16 + g*4 + j);
        O[base + row*EE + dt*16 + lr] = f2bf(oa[dt][j]);
      }
    }
    __syncthreads();
  }
}

// LN over E=512; one wave per row
__global__ __launch_bounds__(256) void lnorm(const u16* __restrict__ in, const float* __restrict__ gg,
                                             const float* __restrict__ bb, u16* __restrict__ outp){
  size_t row = (size_t)blockIdx.x*4 + (threadIdx.x>>6);
  int lane = threadIdx.x & 63;
  const u16* p = in + row*EE + lane*8;
  union{ bf16x8 v; u16 u[8]; } d; d.v = *(const bf16x8*)p;
  float f[8]; float s=0.f;
  #pragma unroll
  for (int j=0;j<8;j++){ f[j]=bf2f(d.u[j]); s+=f[j]; }
  #pragma unroll
  for (int o=1;o<64;o<<=1) s += __shfl_xor(s,o);
  float mu = s*(1.f/512.f);
  float s2=0.f;
  #pragma unroll
  for (int j=0;j<8;j++){ float tt=f[j]-mu; s2+=tt*tt; }
  #pragma unroll
  for (int o=1;o<64;o<<=1) s2 += __shfl_xor(s2,o);
  float rstd = rsqrtf(s2*(1.f/512.f)+1e-5f);
  union{ bf16x8 v; u16 u[8]; } rr;
  #pragma unroll
  for (int j=0;j<8;j++) rr.u[j] = f2bf((f[j]-mu)*rstd*gg[lane*8+j] + bb[lane*8+j]);
  *(bf16x8*)(outp + row*EE + lane*8) = rr.v;
}

// out[b][m][e] = f32(h[r][b][m][e]), m = cb + r
__global__ __launch_bounds__(256) void extract(const u16* __restrict__ h, float* __restrict__ out, int cb){
  int i = blockIdx.x*256 + threadIdx.x;  // over RC*NB*EE
  int e = i & 511;
  int b = (i >> 9) & 7;
  int r = i >> 12;
  int m = cb + r;
  out[((size_t)b*SS + m)*EE + e] = bf2f(h[(((size_t)(r*NB + b))*SS + m)*EE + e]);
}

extern "C" void kernel_launch(void* const* d_in, const int* in_sizes, int n_in,
                              void* d_out, int out_size, void* d_ws, size_t ws_size,
                              hipStream_t stream){
  const float* x   = (const float*)d_in[0];
  const float* Wq  = (const float*)d_in[1];
  const float* bq  = (const float*)d_in[2];
  const float* Wk  = (const float*)d_in[3];
  const float* bk  = (const float*)d_in[4];
  const float* Wv  = (const float*)d_in[5];
  const float* bv  = (const float*)d_in[6];
  const float* Wo  = (const float*)d_in[7];
  const float* bo  = (const float*)d_in[8];
  const float* Wf  = (const float*)d_in[9];
  const float* bfb = (const float*)d_in[10];
  const float* g1  = (const float*)d_in[11];
  const float* b1  = (const float*)d_in[12];
  const float* g2  = (const float*)d_in[13];
  const float* b2  = (const float*)d_in[14];
  float* out = (float*)d_out;

  uint8_t* p = (uint8_t*)d_ws;
  const size_t WSZ = (size_t)NL*EE*EE*2;  // 2 MiB per transposed weight
  u16* WqT = (u16*)p; p += WSZ;
  u16* WkT = (u16*)p; p += WSZ;
  u16* WvT = (u16*)p; p += WSZ;
  u16* WoT = (u16*)p; p += WSZ;
  u16* WfT = (u16*)p; p += WSZ;
  size_t used = (size_t)(p - (uint8_t*)d_ws);

  int RC = 128;  // runs per chunk
  while (RC > 1 && used + 6ull*((size_t)RC<<20) > ws_size) RC >>= 1;

  size_t BUF = (size_t)RC<<20;  // RC*1024 rows * 512 * 2B
  u16* h   = (u16*)p; p += BUF;
  u16* q   = (u16*)p; p += BUF;
  u16* k   = (u16*)p; p += BUF;
  u16* v   = (u16*)p; p += BUF;
  u16* o   = (u16*)p; p += BUF;
  u16* tmp = (u16*)p; p += BUF;

  wtrans<<<4096,256,0,stream>>>(Wq, WqT);
  wtrans<<<4096,256,0,stream>>>(Wk, WkT);
  wtrans<<<4096,256,0,stream>>>(Wv, WvT);
  wtrans<<<4096,256,0,stream>>>(Wo, WoT);
  wtrans<<<4096,256,0,stream>>>(Wf, WfT);

  for (int cb=0; cb<SS; cb+=RC){
    hinit<<<dim3(RC*256),256,0,stream>>>(x, h);
    for (int l=0;l<NL;l++){
      const size_t wo = (size_t)l*EE*EE;
      gemm_bt<0><<<dim3(RC*8,4),256,0,stream>>>(h, WqT+wo, bq+l*EE, nullptr, q);
      gemm_bt<0><<<dim3(RC*8,4),256,0,stream>>>(h, WkT+wo, bk+l*EE, nullptr, k);
      gemm_bt<0><<<dim3(RC*8,4),256,0,stream>>>(h, WvT+wo, bv+l*EE, nullptr, v);
      attn<<<dim3(RC*64),256,0,stream>>>(q, k, v, o, cb);
      gemm_bt<1><<<dim3(RC*8,4),256,0,stream>>>(o, WoT+wo, bo+l*EE, h, tmp);
      lnorm<<<dim3(RC*256),256,0,stream>>>(tmp, g1+l*EE, b1+l*EE, h);
      gemm_bt<2><<<dim3(RC*8,4),256,0,stream>>>(h, WfT+wo, bfb+l*EE, h, tmp);
      lnorm<<<dim3(RC*256),256,0,stream>>>(tmp, g2+l*EE, b2+l*EE, h);
    }
    extract<<<dim3(RC*16),256,0,stream>>>(h, out, cb);
  }
}

// Round 2
// 2332.405 us; speedup vs baseline: 1.5738x; 1.5738x over previous
//
#include <hip/hip_runtime.h>
#include <stdint.h>

typedef unsigned short u16;
typedef __attribute__((ext_vector_type(8))) short bf16x8;
typedef __attribute__((ext_vector_type(4))) float f32x4;

#define EE 512
#define NH 8
#define HDm 64
#define SS 128
#define NB 8
#define NL 4

__device__ __forceinline__ float bf2f(u16 v){ union{uint32_t u; float f;} c; c.u=((uint32_t)v)<<16; return c.f; }
__device__ __forceinline__ u16 f2bf(float f){ union{float f; uint32_t u;} c; c.f=f; uint32_t u=c.u; return (u16)((u + 0x7FFFu + ((u>>16)&1u))>>16); }

__device__ __forceinline__ f32x4 mfma16(bf16x8 a, bf16x8 b, f32x4 c){
  return __builtin_amdgcn_mfma_f32_16x16x32_bf16(a,b,c,0,0,0);
}

__device__ __forceinline__ void gload16(const u16* g, u16* l){
  auto gp = reinterpret_cast<const __attribute__((address_space(1))) uint32_t*>(reinterpret_cast<uintptr_t>(g));
  auto lp = reinterpret_cast<__attribute__((address_space(3))) uint32_t*>(reinterpret_cast<uintptr_t>(l));
  __builtin_amdgcn_global_load_lds(gp, lp, 16, 0, 0);
}

// map blockIdx -> (local run r, unit u) where units-per-run = ((cb+r)/16 + 1) * U.
// runs are grouped by global index /16 (same tile count within a group); <=8 iterations.
__device__ __forceinline__ void run_map(int bid, int cb, int U, int& r, int& u){
  int rr = 0;
  for (;;){
    int g = (cb + rr) >> 4;
    int gend = ((g + 1) << 4) - cb;      // local run index where next group starts
    int upr = (g + 1) * U;               // units per run in this group
    int span = (gend - rr) * upr;
    if (bid < span){ r = rr + bid / upr; u = bid % upr; return; }
    bid -= span; rr = gend;
  }
}

// Wt[l][o][i] = bf16(W[l][i][o])
__global__ __launch_bounds__(256) void wtrans(const float* __restrict__ W, u16* __restrict__ Wt){
  int i = blockIdx.x*256 + threadIdx.x;
  int l = i >> 18;
  int rem = i & 262143;
  int o = rem >> 9, in_ = rem & 511;
  Wt[i] = f2bf(W[((size_t)l<<18) + ((size_t)in_<<9) + (size_t)o]);
}

// h0[p][b][e] = bf16(x[b][p][e])  (single run's worth: 1024 rows)
__global__ __launch_bounds__(256) void hinit(const float* __restrict__ x, u16* __restrict__ h0){
  int i = (blockIdx.x*256 + threadIdx.x)*8;   // elem index in h0, 8 per thread
  int e = i & 511;
  int pb = i >> 9;
  int b = pb & 7, pp = pb >> 3;
  const float* xp = x + (((size_t)b*SS + pp)<<9) + e;
  union{ bf16x8 v; u16 u[8]; } r;
  #pragma unroll
  for (int j=0;j<8;j++) r.u[j] = f2bf(xp[j]);
  *(bf16x8*)(h0 + i) = r.v;
}

// C = A * Bt^T + bias; MODE 0: +bias, 1: +bias+res, 2: relu(+bias)+res
// cb >= 0: run-mapped M tiles (layout [r][p][b][e], 1024 rows/run). cb == -1: plain tiles.
template<int MODE>
__global__ __launch_bounds__(256) void gemm_bt(const u16* __restrict__ A, const u16* __restrict__ Bt,
                                               const float* __restrict__ bias, const u16* __restrict__ res,
                                               u16* __restrict__ out, int cb, size_t res_mask){
  __shared__ u16 As[128*32];
  __shared__ u16 Bs[128*32];
  int t = threadIdx.x;
  size_t m0;
  if (cb < 0){
    m0 = (size_t)blockIdx.x * 128;
  } else {
    int r, tile; run_map(blockIdx.x, cb, 1, r, tile);
    m0 = (size_t)r*1024 + (size_t)tile*128;
  }
  int n0 = blockIdx.y*128;
  int wid=t>>6, lane=t&63;
  int wm=wid>>1, wn=wid&1, lr=lane&15, lk=(lane>>4)*8;
  f32x4 acc[4][4] = {};
  int srow=t>>2, scol=(t&3)*8;
  const u16* gA = A + (m0+(size_t)srow)*EE + scol;
  const u16* gB = Bt + ((size_t)(n0+srow))*EE + scol;
  u16* lA = As + t*8;
  u16* lB = Bs + t*8;
  for (int k0=0;k0<EE;k0+=32){
    __syncthreads();
    gload16(gA+k0, lA);
    gload16(gA+64*EE+k0, lA+2048);
    gload16(gB+k0, lB);
    gload16(gB+64*EE+k0, lB+2048);
    __syncthreads();
    bf16x8 a[4], b[4];
    #pragma unroll
    for (int mi=0;mi<4;mi++) a[mi] = *(const bf16x8*)(As + (wm*64+mi*16+lr)*32 + lk);
    #pragma unroll
    for (int ni=0;ni<4;ni++) b[ni] = *(const bf16x8*)(Bs + (wn*64+ni*16+lr)*32 + lk);
    #pragma unroll
    for (int mi=0;mi<4;mi++)
      #pragma unroll
      for (int ni=0;ni<4;ni++)
        acc[mi][ni] = mfma16(a[mi], b[ni], acc[mi][ni]);
  }
  int g4 = lane>>4;
  #pragma unroll
  for (int ni=0;ni<4;ni++){
    int col = n0 + wn*64 + ni*16 + lr;
    float bv = bias[col];
    #pragma unroll
    for (int mi=0;mi<4;mi++){
      #pragma unroll
      for (int j=0;j<4;j++){
        size_t row = m0 + (size_t)(wm*64 + mi*16 + g4*4 + j);
        float v = acc[mi][ni][j] + bv;
        if (MODE==2) v = fmaxf(v, 0.f);
        if (MODE>=1) v += bf2f(res[(row & res_mask)*EE + col]);
        out[row*EE + col] = f2bf(v);
      }
    }
  }
}

// one block per (run, batch, head); layout [r][p][b][e]; shared_qkv=1 -> q/k/v run-stride 0
__global__ __launch_bounds__(256) void attn(const u16* __restrict__ Q, const u16* __restrict__ K,
                                            const u16* __restrict__ V, u16* __restrict__ O,
                                            int cb, int shared_qkv){
  __shared__ u16 Ks[128*72];     // [key][d], pad 8
  __shared__ u16 Vt[64*136];     // [d][key], pad 8
  __shared__ u16 Ps[4][16*136];  // per-wave P [q][key], pad 8
  int t = threadIdx.x;
  int idx = blockIdx.x;
  int hh = idx & 7, b = (idx>>3)&7, r = idx>>6;
  int m_run = cb + r;
  const size_t RSTRIDE = (size_t)SS*NB*EE;   // elems per run
  size_t rbase = shared_qkv ? 0 : (size_t)r*RSTRIDE;
  size_t obase = (size_t)r*RSTRIDE;
  size_t hb = (size_t)b*EE + hh*HDm;
  for (int i=t; i<1024; i+=256){
    int row=i>>3, c=(i&7)*8;
    *(uint4*)(Ks + row*72 + c) = *(const uint4*)(K + rbase + (size_t)row*NB*EE + hb + c);
  }
  for (int i=t; i<1024; i+=256){
    int row=i>>3, c=(i&7)*8;
    uint4 raw = *(const uint4*)(V + rbase + (size_t)row*NB*EE + hb + c);
    const u16* pv = (const u16*)&raw;
    #pragma unroll
    for (int j=0;j<8;j++) Vt[(c+j)*136 + row] = pv[j];
  }
  __syncthreads();
  int wid=t>>6, lane=t&63, lr=lane&15, g=lane>>4, lk=(lane>>4)*8;
  int nkc = m_run/32 + 1;   // 1..4 key chunks of 32
  int nkt = nkc*2;          // 2..8 key tiles of 16
  int nqt = m_run/16 + 1;   // needed q tiles (matches GEMM tile rounding)
  u16* Pw = Ps[wid];
  for (int iq=0; iq<2; iq++){
    int qt = wid*2 + iq;
    if (qt >= nqt) continue;            // no block-level sync inside loop: safe
    const u16* qrow = Q + rbase + (size_t)(qt*16+lr)*NB*EE + hb;
    bf16x8 qa0 = *(const bf16x8*)(qrow + lk);
    bf16x8 qa1 = *(const bf16x8*)(qrow + 32 + lk);
    f32x4 sc[8];
    #pragma unroll
    for (int kt=0;kt<8;kt++){
      if (kt < nkt){
        f32x4 c = {};
        bf16x8 kb0 = *(const bf16x8*)(Ks + (kt*16+lr)*72 + lk);
        bf16x8 kb1 = *(const bf16x8*)(Ks + (kt*16+lr)*72 + 32 + lk);
        c = mfma16(qa0, kb0, c);
        c = mfma16(qa1, kb1, c);
        int key = kt*16 + lr;
        #pragma unroll
        for (int i2=0;i2<4;i2++)
          sc[kt][i2] = (key <= m_run) ? c[i2]*0.125f : -1e9f;
      }
    }
    #pragma unroll
    for (int i2=0;i2<4;i2++){
      float v = -3.0e38f;
      #pragma unroll
      for (int kt=0;kt<8;kt++) if (kt<nkt) v = fmaxf(v, sc[kt][i2]);
      v = fmaxf(v, __shfl_xor(v,1));
      v = fmaxf(v, __shfl_xor(v,2));
      v = fmaxf(v, __shfl_xor(v,4));
      v = fmaxf(v, __shfl_xor(v,8));
      float s = 0.f;
      #pragma unroll
      for (int kt=0;kt<8;kt++) if (kt<nkt){ float e2=__expf(sc[kt][i2]-v); sc[kt][i2]=e2; s+=e2; }
      s += __shfl_xor(s,1); s += __shfl_xor(s,2); s += __shfl_xor(s,4); s += __shfl_xor(s,8);
      float inv = 1.f/s;
      #pragma unroll
      for (int kt=0;kt<8;kt++) if (kt<nkt) sc[kt][i2] *= inv;
    }
    #pragma unroll
    for (int kt=0;kt<8;kt++) if (kt<nkt){
      #pragma unroll
      for (int i2=0;i2<4;i2++)
        Pw[(g*4+i2)*136 + kt*16 + lr] = f2bf(sc[kt][i2]);
    }
    f32x4 oa[4] = {};
    #pragma unroll
    for (int kc=0;kc<4;kc++) if (kc<nkc){
      bf16x8 pa = *(const bf16x8*)(Pw + lr*136 + kc*32 + lk);
      #pragma unroll
      for (int dt=0;dt<4;dt++){
        bf16x8 vb = *(const bf16x8*)(Vt + (dt*16+lr)*136 + kc*32 + lk);
        oa[dt] = mfma16(pa, vb, oa[dt]);
      }
    }
    #pragma unroll
    for (int dt=0;dt<4;dt++){
      #pragma unroll
      for (int j=0;j<4;j++){
        size_t prow = (size_t)(qt*16 + g*4 + j);
        O[obase + prow*NB*EE + hb + dt*16 + lr] = f2bf(oa[dt][j]);
      }
    }
  }
}

// LN over E=512; one wave per row; run-mapped rows (U=32 -> 128 rows per tile)
__global__ __launch_bounds__(256) void lnorm(const u16* __restrict__ in, const float* __restrict__ gg,
                                             const float* __restrict__ bb, u16* __restrict__ outp, int cb){
  int r, u; run_map(blockIdx.x, cb, 32, r, u);
  size_t row = (size_t)r*1024 + (size_t)u*4 + (threadIdx.x>>6);
  int lane = threadIdx.x & 63;
  const u16* p = in + row*EE + lane*8;
  union{ bf16x8 v; u16 u[8]; } d; d.v = *(const bf16x8*)p;
  float f[8]; float s=0.f;
  #pragma unroll
  for (int j=0;j<8;j++){ f[j]=bf2f(d.u[j]); s+=f[j]; }
  #pragma unroll
  for (int o=1;o<64;o<<=1) s += __shfl_xor(s,o);
  float mu = s*(1.f/512.f);
  float s2=0.f;
  #pragma unroll
  for (int j=0;j<8;j++){ float tt=f[j]-mu; s2+=tt*tt; }
  #pragma unroll
  for (int o=1;o<64;o<<=1) s2 += __shfl_xor(s2,o);
  float rstd = rsqrtf(s2*(1.f/512.f)+1e-5f);
  union{ bf16x8 v; u16 u[8]; } rr;
  #pragma unroll
  for (int j=0;j<8;j++) rr.u[j] = f2bf((f[j]-mu)*rstd*gg[lane*8+j] + bb[lane*8+j]);
  *(bf16x8*)(outp + row*EE + lane*8) = rr.v;
}

// out[b][m][e] = f32(h[r][p=m][b][e]), m = cb + r
__global__ __launch_bounds__(256) void extract(const u16* __restrict__ h, float* __restrict__ out, int cb){
  int i = blockIdx.x*256 + threadIdx.x;  // over RC*NB*EE
  int e = i & 511;
  int b = (i >> 9) & 7;
  int r = i >> 12;
  int m = cb + r;
  out[((size_t)b*SS + m)*EE + e] = bf2f(h[(((size_t)r*SS + m)*NB + b)*EE + e]);
}

extern "C" void kernel_launch(void* const* d_in, const int* in_sizes, int n_in,
                              void* d_out, int out_size, void* d_ws, size_t ws_size,
                              hipStream_t stream){
  const float* x   = (const float*)d_in[0];
  const float* Wq  = (const float*)d_in[1];
  const float* bq  = (const float*)d_in[2];
  const float* Wk  = (const float*)d_in[3];
  const float* bk  = (const float*)d_in[4];
  const float* Wv  = (const float*)d_in[5];
  const float* bv  = (const float*)d_in[6];
  const float* Wo  = (const float*)d_in[7];
  const float* bo  = (const float*)d_in[8];
  const float* Wf  = (const float*)d_in[9];
  const float* bfb = (const float*)d_in[10];
  const float* g1  = (const float*)d_in[11];
  const float* b1  = (const float*)d_in[12];
  const float* g2  = (const float*)d_in[13];
  const float* b2  = (const float*)d_in[14];
  float* out = (float*)d_out;

  uint8_t* p = (uint8_t*)d_ws;
  const size_t WSZ = (size_t)NL*EE*EE*2;  // 2 MiB per transposed weight
  u16* WqT = (u16*)p; p += WSZ;
  u16* WkT = (u16*)p; p += WSZ;
  u16* WvT = (u16*)p; p += WSZ;
  u16* WoT = (u16*)p; p += WSZ;
  u16* WfT = (u16*)p; p += WSZ;
  const size_t RUN = (size_t)SS*NB*EE*2;  // 1 MiB: one run's activations
  u16* h0 = (u16*)p; p += RUN;
  u16* q0 = (u16*)p; p += RUN;
  u16* k0 = (u16*)p; p += RUN;
  u16* v0 = (u16*)p; p += RUN;
  size_t used = (size_t)(p - (uint8_t*)d_ws);

  int RC = 128;  // runs per chunk
  while (RC > 1 && used + 6ull*((size_t)RC<<20) > ws_size) RC >>= 1;

  size_t BUF = (size_t)RC<<20;
  u16* h   = (u16*)p; p += BUF;
  u16* q   = (u16*)p; p += BUF;
  u16* k   = (u16*)p; p += BUF;
  u16* v   = (u16*)p; p += BUF;
  u16* o   = (u16*)p; p += BUF;
  u16* tmp = (u16*)p; p += BUF;

  const size_t NOMASK = ~(size_t)0;

  wtrans<<<4096,256,0,stream>>>(Wq, WqT);
  wtrans<<<4096,256,0,stream>>>(Wk, WkT);
  wtrans<<<4096,256,0,stream>>>(Wv, WvT);
  wtrans<<<4096,256,0,stream>>>(Wo, WoT);
  wtrans<<<4096,256,0,stream>>>(Wf, WfT);

  // layer-0 QKV is identical for every run: compute once (1024 rows)
  hinit<<<256,256,0,stream>>>(x, h0);
  gemm_bt<0><<<dim3(8,4),256,0,stream>>>(h0, WqT, bq, nullptr, q0, -1, NOMASK);
  gemm_bt<0><<<dim3(8,4),256,0,stream>>>(h0, WkT, bk, nullptr, k0, -1, NOMASK);
  gemm_bt<0><<<dim3(8,4),256,0,stream>>>(h0, WvT, bv, nullptr, v0, -1, NOMASK);

  for (int cb=0; cb<SS; cb+=RC){
    int tiles = 0;
    for (int r2=0;r2<RC;r2++) tiles += (cb + r2)/16 + 1;

    // layer 0
    attn<<<dim3(RC*64),256,0,stream>>>(q0, k0, v0, o, cb, 1);
    gemm_bt<1><<<dim3(tiles,4),256,0,stream>>>(o, WoT, bo, h0, tmp, cb, (size_t)1023);
    lnorm<<<dim3(tiles*32),256,0,stream>>>(tmp, g1, b1, h, cb);
    gemm_bt<2><<<dim3(tiles,4),256,0,stream>>>(h, WfT, bfb, h, tmp, cb, NOMASK);
    lnorm<<<dim3(tiles*32),256,0,stream>>>(tmp, g2, b2, h, cb);

    // layers 1..3
    for (int l=1;l<NL;l++){
      const size_t wo = (size_t)l*EE*EE;
      gemm_bt<0><<<dim3(tiles,4),256,0,stream>>>(h, WqT+wo, bq+l*EE, nullptr, q, cb, NOMASK);
      gemm_bt<0><<<dim3(tiles,4),256,0,stream>>>(h, WkT+wo, bk+l*EE, nullptr, k, cb, NOMASK);
      gemm_bt<0><<<dim3(tiles,4),256,0,stream>>>(h, WvT+wo, bv+l*EE, nullptr, v, cb, NOMASK);
      attn<<<dim3(RC*64),256,0,stream>>>(q, k, v, o, cb, 0);
      gemm_bt<1><<<dim3(tiles,4),256,0,stream>>>(o, WoT+wo, bo+l*EE, h, tmp, cb, NOMASK);
      lnorm<<<dim3(tiles*32),256,0,stream>>>(tmp, g1+l*EE, b1+l*EE, h, cb);
      gemm_bt<2><<<dim3(tiles,4),256,0,stream>>>(h, WfT+wo, bfb+l*EE, h, tmp, cb, NOMASK);
      lnorm<<<dim3(tiles*32),256,0,stream>>>(tmp, g2+l*EE, b2+l*EE, h, cb);
    }
    extract<<<dim3(RC*16),256,0,stream>>>(h, out, cb);
  }
}